// Round 1
// baseline (402.489 us; speedup 1.0000x reference)
//
#include <hip/hip_runtime.h>

// NONA: out = softmax(-cdist(x, x_n), axis=1) @ y
//   x[4096,1024] f32, x_n[8192,1024] f32, y[8192,128] f32, log_T unused.
//
// R1 design:
//  * sim = -sqrt(max(xsq_i + xnsq_j - 2*dot_ij, 0)); since sim in [-60,0],
//    exp(sim) is a normal f32/bf16 -> NO online-max softmax needed. Accumulate
//    l = sum(exp), O = sum(exp*y) and normalize at the end.
//  * dot via bf16 MFMA 16x16x32 (exact f32 norms), flash-fused, split-M=8
//    with a tiny combine kernel (partials in d_ws).
//  * m97-class structure: 128x128 tile, 4 waves (64x64 each), BK=64,
//    global_load_lds(16B) staging, XOR-granule swizzle (src-side) for
//    conflict-free ds_read_b128. Static LDS = exactly 64 KiB -> 2 blocks/CU.
//
// ws layout (bytes): xb@0 (8Mi) | xnb@8Mi (16Mi) | yT@24Mi (2Mi) |
//   xsq@26Mi (16Ki) | xnsq@26Mi+64Ki (32Ki) | Opart@27Mi (16Mi) | Lpart@43Mi (128Ki)

#define N_ 4096
#define M_ 8192
#define D_ 1024
#define C_ 128
#define SPLIT 8
#define MCOLS (M_ / SPLIT)   // 1024
#define BM 128
#define BN 128
#define BK 64
#define NBN (MCOLS / BN)     // 8
#define NKK (D_ / BK)        // 16

typedef __bf16 bf16;
typedef __attribute__((ext_vector_type(8))) __bf16 bf16x8;
typedef __attribute__((ext_vector_type(4))) __bf16 bf16x4;
typedef __attribute__((ext_vector_type(4))) float f32x4;

__device__ __forceinline__ void async_copy16(const bf16* gp, void* lp) {
  __builtin_amdgcn_global_load_lds(
      (__attribute__((address_space(1))) void*)const_cast<bf16*>(gp),
      (__attribute__((address_space(3))) void*)lp, 16, 0, 0);
}

// Swizzled LDS byte offset for a [rows][64]-bf16 tile (128 B rows):
// 16B-granule XOR with row&7. Staging stores src granule (g ^ row&7) at
// granule g (linear dest), so reading granule (g ^ row&7) returns src granule g.
__device__ __forceinline__ int swz(int row, int gran) {
  return (row << 7) + ((gran ^ (row & 7)) << 4);
}

// Stage a [128][64]-bf16 tile (16 KiB) global->LDS, source pre-swizzled.
__device__ __forceinline__ void stage16k(const bf16* src, int ld, char* lds, int tid) {
  const int lane = tid & 63, wave = tid >> 6;
#pragma unroll
  for (int j = 0; j < 4; ++j) {
    const int ch  = j * 4 + wave;            // wave-uniform chunk id
    const int off = ch * 1024 + lane * 16;   // linear byte in tile
    const int row = off >> 7;
    const int grs = ((off >> 4) & 7) ^ (row & 7);
    async_copy16(src + (size_t)row * ld + grs * 8, lds + ch * 1024);
  }
}

__global__ __launch_bounds__(256, 2)
void nona_main(const bf16* __restrict__ xb, const bf16* __restrict__ xnb,
               const bf16* __restrict__ yT, const float* __restrict__ xsq,
               const float* __restrict__ xnsq, float* __restrict__ Opart,
               float* __restrict__ Lpart)
{
  __shared__ __align__(16) char Asm[16384];   // x tile   [128][64] bf16, swizzled
  __shared__ __align__(16) char Bsm[16384];   // x_n tile [128][64] bf16, swizzled
  __shared__ __align__(16) char Vsm[16384];   // yT tile  [128 C][64 xn] bf16, swizzled
  __shared__ __align__(16) char Psm[16384];   // P half   [128][64] bf16, swizzled

  const int tid  = threadIdx.x;
  const int lane = tid & 63;
  const int wave = tid >> 6;
  const int wr = wave >> 1, wc = wave & 1;
  const int g = lane >> 4, c = lane & 15;

  const int bid  = blockIdx.x;
  const int s    = bid & 7;         // split -> XCD (round-robin) for L2 locality
  const int rb   = bid >> 3;
  const int row0 = rb * BM;
  const int col0 = s * MCOLS;

  float xsqr[4][4];
#pragma unroll
  for (int rf = 0; rf < 4; ++rf)
#pragma unroll
    for (int r = 0; r < 4; ++r)
      xsqr[rf][r] = xsq[row0 + wr * 64 + rf * 16 + g * 4 + r];

  f32x4 Oacc[4][4];
  const f32x4 zero = {0.f, 0.f, 0.f, 0.f};
#pragma unroll
  for (int rf = 0; rf < 4; ++rf)
#pragma unroll
    for (int cf = 0; cf < 4; ++cf) Oacc[rf][cf] = zero;
  float lpart[4][4] = {};

  auto writeP = [&](f32x4 (&w)[4][4], int half) {
    if (wc == half) {
#pragma unroll
      for (int rf = 0; rf < 4; ++rf)
#pragma unroll
        for (int cf = 0; cf < 4; ++cf)
#pragma unroll
          for (int r = 0; r < 4; ++r) {
            const int row = wr * 64 + rf * 16 + g * 4 + r;
            const int col = cf * 16 + c;                    // xn within half
            const int byte = (row << 7) + (((col >> 3) ^ (row & 7)) << 4) + (col & 7) * 2;
            *(bf16*)(Psm + byte) = (bf16)w[rf][cf][r];
          }
    }
  };
  auto pvStep = [&]() {
#pragma unroll
    for (int ks = 0; ks < 2; ++ks) {
      bf16x8 pa[4];
#pragma unroll
      for (int rf = 0; rf < 4; ++rf)
        pa[rf] = *(const bf16x8*)(Psm + swz(wr * 64 + rf * 16 + c, ks * 4 + g));
#pragma unroll
      for (int cf = 0; cf < 4; ++cf) {
        bf16x8 vb = *(const bf16x8*)(Vsm + swz(wc * 64 + cf * 16 + c, ks * 4 + g));
#pragma unroll
        for (int rf = 0; rf < 4; ++rf)
          Oacc[rf][cf] = __builtin_amdgcn_mfma_f32_16x16x32_bf16(pa[rf], vb, Oacc[rf][cf], 0, 0, 0);
      }
    }
  };

  for (int bn = 0; bn < NBN; ++bn) {
    const int colbase = col0 + bn * BN;

    f32x4 Sacc[4][4];
#pragma unroll
    for (int rf = 0; rf < 4; ++rf)
#pragma unroll
      for (int cf = 0; cf < 4; ++cf) Sacc[rf][cf] = zero;

#pragma unroll 1
    for (int kk = 0; kk < NKK; ++kk) {
      __syncthreads();   // prior readers of Asm/Bsm (and Vsm/Psm at kk==0) done
      stage16k(xb + (size_t)row0 * D_ + kk * BK, D_, Asm, tid);
      stage16k(xnb + (size_t)colbase * D_ + kk * BK, D_, Bsm, tid);
      if (kk == 0) stage16k(yT + colbase, M_, Vsm, tid);   // V half 0
      __syncthreads();   // staging complete (vmcnt(0) drained by barrier)
#pragma unroll
      for (int ks = 0; ks < 2; ++ks) {
        bf16x8 af[4];
#pragma unroll
        for (int rf = 0; rf < 4; ++rf)
          af[rf] = *(const bf16x8*)(Asm + swz(wr * 64 + rf * 16 + c, ks * 4 + g));
#pragma unroll
        for (int cf = 0; cf < 4; ++cf) {
          bf16x8 bv = *(const bf16x8*)(Bsm + swz(wc * 64 + cf * 16 + c, ks * 4 + g));
#pragma unroll
          for (int rf = 0; rf < 4; ++rf)
            Sacc[rf][cf] = __builtin_amdgcn_mfma_f32_16x16x32_bf16(af[rf], bv, Sacc[rf][cf], 0, 0, 0);
        }
      }
    }

    // elementwise: w = exp(-sqrt(max(xsq + xnsq - 2*dot, 0))); accumulate l
#pragma unroll
    for (int cf = 0; cf < 4; ++cf) {
      const float nsq = xnsq[colbase + wc * 64 + cf * 16 + c];
#pragma unroll
      for (int rf = 0; rf < 4; ++rf)
#pragma unroll
        for (int r = 0; r < 4; ++r) {
          float d2 = xsqr[rf][r] + nsq - 2.0f * Sacc[rf][cf][r];
          d2 = fmaxf(d2, 0.0f);
          const float wv = __expf(-sqrtf(d2));
          lpart[rf][r] += wv;
          Sacc[rf][cf][r] = wv;     // reuse Sacc as w storage
        }
    }

    // half 0: waves wc==0 hold cols 0..63 of this tile
    writeP(Sacc, 0);
    __syncthreads();                 // P(h0) visible; Vsm(h0) staged at kk==0
    pvStep();
    __syncthreads();                 // PV(h0) reads done -> Vsm/Psm reusable
    stage16k(yT + colbase + 64, M_, Vsm, tid);   // V half 1
    writeP(Sacc, 1);
    __syncthreads();                 // vmcnt(0)+barrier: V(h1)+P(h1) ready
    pvStep();
    // next bn's first barrier protects Vsm/Psm restage
  }

  // ---- epilogue: l reduction (deterministic: shfl + single writer) ----
  float (*Lred)[2] = reinterpret_cast<float(*)[2]>(Asm);  // Asm is dead now
#pragma unroll
  for (int rf = 0; rf < 4; ++rf)
#pragma unroll
    for (int r = 0; r < 4; ++r) {
      float v = lpart[rf][r];
      v += __shfl_xor(v, 1);
      v += __shfl_xor(v, 2);
      v += __shfl_xor(v, 4);
      v += __shfl_xor(v, 8);
      if (c == 0) Lred[wr * 64 + rf * 16 + g * 4 + r][wc] = v;
    }
  __syncthreads();
  if (tid < 128)
    Lpart[(size_t)s * N_ + row0 + tid] = Lred[tid][0] + Lred[tid][1];

  float* ob = Opart + ((size_t)s * N_ + row0) * C_;
#pragma unroll
  for (int rf = 0; rf < 4; ++rf)
#pragma unroll
    for (int cf = 0; cf < 4; ++cf)
#pragma unroll
      for (int r = 0; r < 4; ++r)
        ob[(wr * 64 + rf * 16 + g * 4 + r) * C_ + wc * 64 + cf * 16 + c] = Oacc[rf][cf][r];
}

// row-wise: f32 -> bf16 copy + exact f32 squared norm
__global__ void prep_rows(const float* __restrict__ src, bf16* __restrict__ dst,
                          float* __restrict__ sq)
{
  const int row = blockIdx.x;
  const int t = threadIdx.x;                   // 256 threads, 4 f32 each
  const float4 v = reinterpret_cast<const float4*>(src + (size_t)row * D_)[t];
  float ss = v.x * v.x + v.y * v.y + v.z * v.z + v.w * v.w;
  bf16x4 hv;
  hv[0] = (bf16)v.x; hv[1] = (bf16)v.y; hv[2] = (bf16)v.z; hv[3] = (bf16)v.w;
  *reinterpret_cast<bf16x4*>(dst + (size_t)row * D_ + t * 4) = hv;
#pragma unroll
  for (int o = 32; o > 0; o >>= 1) ss += __shfl_down(ss, o);
  __shared__ float red[4];
  if ((t & 63) == 0) red[t >> 6] = ss;
  __syncthreads();
  if (t == 0) sq[row] = red[0] + red[1] + red[2] + red[3];
}

// y[8192][128] f32 -> yT[128][8192] bf16
__global__ void prep_yT(const float* __restrict__ y, bf16* __restrict__ yT)
{
  __shared__ bf16 tile[C_][72];
  const int m0 = blockIdx.x * 64;
  const int t = threadIdx.x;
#pragma unroll
  for (int i = 0; i < 32; ++i) {
    const int idx = i * 256 + t;               // 0..8191
    const int ml = idx >> 7, cc = idx & 127;
    tile[cc][ml] = (bf16)y[(size_t)(m0 + ml) * C_ + cc];
  }
  __syncthreads();
#pragma unroll
  for (int i = 0; i < 32; ++i) {
    const int idx = i * 256 + t;
    const int cc = idx >> 6, ml = idx & 63;
    yT[(size_t)cc * M_ + m0 + ml] = tile[cc][ml];
  }
}

__global__ void combine(const float* __restrict__ Opart, const float* __restrict__ Lpart,
                        float* __restrict__ out)
{
  const int i = blockIdx.x * 256 + threadIdx.x;   // < N_*C_
  const int row = i >> 7;
  float o = 0.f, l = 0.f;
#pragma unroll
  for (int s = 0; s < SPLIT; ++s) {
    o += Opart[(size_t)s * N_ * C_ + i];
    l += Lpart[(size_t)s * N_ + row];
  }
  out[i] = o / l;
}

extern "C" void kernel_launch(void* const* d_in, const int* in_sizes, int n_in,
                              void* d_out, int out_size, void* d_ws, size_t ws_size,
                              hipStream_t stream)
{
  const float* x  = (const float*)d_in[0];
  const float* xn = (const float*)d_in[1];
  const float* y  = (const float*)d_in[2];
  // d_in[3] = log_T: computed-but-unused in the reference forward.
  float* out = (float*)d_out;

  char* ws = (char*)d_ws;
  bf16*  xb    = (bf16*)(ws);
  bf16*  xnb   = (bf16*)(ws + (size_t)(8)  * 1024 * 1024);
  bf16*  yT    = (bf16*)(ws + (size_t)(24) * 1024 * 1024);
  float* xsq   = (float*)(ws + (size_t)(26) * 1024 * 1024);
  float* xnsq  = (float*)(ws + (size_t)(26) * 1024 * 1024 + 64 * 1024);
  float* Opart = (float*)(ws + (size_t)(27) * 1024 * 1024);
  float* Lpart = (float*)(ws + (size_t)(43) * 1024 * 1024);

  prep_rows<<<N_, 256, 0, stream>>>(x, xb, xsq);
  prep_rows<<<M_, 256, 0, stream>>>(xn, xnb, xnsq);
  prep_yT<<<M_ / 64, 256, 0, stream>>>(y, yT);
  nona_main<<<(N_ / BM) * SPLIT, 256, 0, stream>>>(xb, xnb, yT, xsq, xnsq, Opart, Lpart);
  combine<<<(N_ * C_) / 256, 256, 0, stream>>>(Opart, Lpart, out);
}

// Round 2
// 382.102 us; speedup vs baseline: 1.0534x; 1.0534x over previous
//
#include <hip/hip_runtime.h>

// NONA: out = softmax(-cdist(x, x_n), axis=1) @ y
//   x[4096,1024] f32, x_n[8192,1024] f32, y[8192,128] f32, log_T unused.
//
// R2 changes (R1 was occupancy-bound: 256 blocks = 1 block/CU, Occ 11%):
//  * runtime SPLIT (8/16/32 chosen from ws_size) -> grid 256/512/1024 blocks,
//    targeting 3 blocks/CU co-residency for barrier-stall overlap (m114).
//  * LDS 64Ki -> 48Ki: Psm aliases Asm (disjoint in time; +2 barriers/bn).
//    48Ki + 128 VGPR -> 3 blocks/CU capacity. __launch_bounds__(256,3).
//  * everything else identical (m97-class 2-barrier loop, src-side XOR
//    swizzle + global_load_lds(16B), no-online-max flash softmax).
//
// ws layout (bytes): xb@0 (8Mi) | xnb@8Mi (16Mi) | yT@24Mi (2Mi) |
//   xsq@26Mi (16Ki) | xnsq@+16Ki (32Ki) | Lpart@26Mi+48Ki (<=512Ki) |
//   Opart@27Mi (split*2Mi)

#define N_ 4096
#define M_ 8192
#define D_ 1024
#define C_ 128
#define BM 128
#define BN 128
#define BK 64
#define NKK (D_ / BK)        // 16

typedef __bf16 bf16;
typedef __attribute__((ext_vector_type(8))) __bf16 bf16x8;
typedef __attribute__((ext_vector_type(4))) __bf16 bf16x4;
typedef __attribute__((ext_vector_type(4))) float f32x4;

__device__ __forceinline__ void async_copy16(const bf16* gp, void* lp) {
  __builtin_amdgcn_global_load_lds(
      (__attribute__((address_space(1))) void*)const_cast<bf16*>(gp),
      (__attribute__((address_space(3))) void*)lp, 16, 0, 0);
}

// Swizzled LDS byte offset for a [rows][64]-bf16 tile (128 B rows):
// 16B-granule XOR with row&7. Staging stores src granule (g ^ row&7) at
// granule g (linear dest), so reading granule (g ^ row&7) returns src granule g.
__device__ __forceinline__ int swz(int row, int gran) {
  return (row << 7) + ((gran ^ (row & 7)) << 4);
}

// Stage a [128][64]-bf16 tile (16 KiB) global->LDS, source pre-swizzled.
__device__ __forceinline__ void stage16k(const bf16* src, int ld, char* lds, int tid) {
  const int lane = tid & 63, wave = tid >> 6;
#pragma unroll
  for (int j = 0; j < 4; ++j) {
    const int ch  = j * 4 + wave;            // wave-uniform chunk id
    const int off = ch * 1024 + lane * 16;   // linear byte in tile
    const int row = off >> 7;
    const int grs = ((off >> 4) & 7) ^ (row & 7);
    async_copy16(src + (size_t)row * ld + grs * 8, lds + ch * 1024);
  }
}

__global__ __launch_bounds__(256, 3)
void nona_main(const bf16* __restrict__ xb, const bf16* __restrict__ xnb,
               const bf16* __restrict__ yT, const float* __restrict__ xsq,
               const float* __restrict__ xnsq, float* __restrict__ Opart,
               float* __restrict__ Lpart,
               int split_mask, int split_shift, int mcols, int nbn)
{
  __shared__ __align__(16) char Asm[16384];   // x tile [128][64] bf16, swizzled; aliased as Psm
  __shared__ __align__(16) char Bsm[16384];   // x_n tile [128][64] bf16, swizzled
  __shared__ __align__(16) char Vsm[16384];   // yT tile [128 C][64 xn] bf16, swizzled
  char* const Psm = Asm;                      // P half [128][64], time-disjoint with A

  const int tid  = threadIdx.x;
  const int lane = tid & 63;
  const int wave = tid >> 6;
  const int wr = wave >> 1, wc = wave & 1;
  const int g = lane >> 4, c = lane & 15;

  const int bid  = blockIdx.x;
  const int s    = bid & split_mask;   // split id; bid%8 -> XCD round-robin locality
  const int rb   = bid >> split_shift;
  const int row0 = rb * BM;
  const int col0 = s * mcols;

  float xsqr[4][4];
#pragma unroll
  for (int rf = 0; rf < 4; ++rf)
#pragma unroll
    for (int r = 0; r < 4; ++r)
      xsqr[rf][r] = xsq[row0 + wr * 64 + rf * 16 + g * 4 + r];

  f32x4 Oacc[4][4];
  const f32x4 zero = {0.f, 0.f, 0.f, 0.f};
#pragma unroll
  for (int rf = 0; rf < 4; ++rf)
#pragma unroll
    for (int cf = 0; cf < 4; ++cf) Oacc[rf][cf] = zero;
  float lpart[4][4] = {};

  auto writeP = [&](f32x4 (&w)[4][4], int half) {
    if (wc == half) {
#pragma unroll
      for (int rf = 0; rf < 4; ++rf)
#pragma unroll
        for (int cf = 0; cf < 4; ++cf)
#pragma unroll
          for (int r = 0; r < 4; ++r) {
            const int row = wr * 64 + rf * 16 + g * 4 + r;
            const int col = cf * 16 + c;                    // xn within half
            const int byte = (row << 7) + (((col >> 3) ^ (row & 7)) << 4) + (col & 7) * 2;
            *(bf16*)(Psm + byte) = (bf16)w[rf][cf][r];
          }
    }
  };
  auto pvStep = [&]() {
#pragma unroll
    for (int ks = 0; ks < 2; ++ks) {
      bf16x8 pa[4];
#pragma unroll
      for (int rf = 0; rf < 4; ++rf)
        pa[rf] = *(const bf16x8*)(Psm + swz(wr * 64 + rf * 16 + c, ks * 4 + g));
#pragma unroll
      for (int cf = 0; cf < 4; ++cf) {
        bf16x8 vb = *(const bf16x8*)(Vsm + swz(wc * 64 + cf * 16 + c, ks * 4 + g));
#pragma unroll
        for (int rf = 0; rf < 4; ++rf)
          Oacc[rf][cf] = __builtin_amdgcn_mfma_f32_16x16x32_bf16(pa[rf], vb, Oacc[rf][cf], 0, 0, 0);
      }
    }
  };

  for (int bn = 0; bn < nbn; ++bn) {
    const int colbase = col0 + bn * BN;

    f32x4 Sacc[4][4];
#pragma unroll
    for (int rf = 0; rf < 4; ++rf)
#pragma unroll
      for (int cf = 0; cf < 4; ++cf) Sacc[rf][cf] = zero;

#pragma unroll 1
    for (int kk = 0; kk < NKK; ++kk) {
      __syncthreads();   // (a) prior readers of Asm(=Psm)/Bsm/Vsm done
      stage16k(xb + (size_t)row0 * D_ + kk * BK, D_, Asm, tid);
      stage16k(xnb + (size_t)colbase * D_ + kk * BK, D_, Bsm, tid);
      if (kk == 0) stage16k(yT + colbase, M_, Vsm, tid);   // V half 0
      __syncthreads();   // (b) staging complete (vmcnt(0) drained at barrier)
#pragma unroll
      for (int ks = 0; ks < 2; ++ks) {
        bf16x8 af[4];
#pragma unroll
        for (int rf = 0; rf < 4; ++rf)
          af[rf] = *(const bf16x8*)(Asm + swz(wr * 64 + rf * 16 + c, ks * 4 + g));
#pragma unroll
        for (int cf = 0; cf < 4; ++cf) {
          bf16x8 bv = *(const bf16x8*)(Bsm + swz(wc * 64 + cf * 16 + c, ks * 4 + g));
#pragma unroll
          for (int rf = 0; rf < 4; ++rf)
            Sacc[rf][cf] = __builtin_amdgcn_mfma_f32_16x16x32_bf16(af[rf], bv, Sacc[rf][cf], 0, 0, 0);
        }
      }
    }

    // elementwise: w = exp(-sqrt(max(xsq + xnsq - 2*dot, 0))); accumulate l
#pragma unroll
    for (int cf = 0; cf < 4; ++cf) {
      const float nsq = xnsq[colbase + wc * 64 + cf * 16 + c];
#pragma unroll
      for (int rf = 0; rf < 4; ++rf)
#pragma unroll
        for (int r = 0; r < 4; ++r) {
          float d2 = xsqr[rf][r] + nsq - 2.0f * Sacc[rf][cf][r];
          d2 = fmaxf(d2, 0.0f);
          const float wv = __expf(-sqrtf(d2));
          lpart[rf][r] += wv;
          Sacc[rf][cf][r] = wv;     // reuse Sacc as w storage
        }
    }

    __syncthreads();                 // (c) K-loop Asm reads done before P write (alias!)
    writeP(Sacc, 0);                 // waves wc==0 hold cols 0..63 of this tile
    __syncthreads();                 // (d) P(h0) visible; Vsm(h0) staged at kk==0
    pvStep();
    __syncthreads();                 // (e) PV(h0) reads of Psm/Vsm done
    stage16k(yT + colbase + 64, M_, Vsm, tid);   // V half 1
    writeP(Sacc, 1);
    __syncthreads();                 // (f) vmcnt(0)+barrier: V(h1)+P(h1) ready
    pvStep();
    // next bn's barrier (a) protects Asm(=Psm)/Bsm/Vsm restage vs pvStep reads
  }

  // ---- epilogue: l reduction (deterministic: shfl + single writer) ----
  __syncthreads();                   // (g) pvStep(h1) reads of Psm(=Asm) done
  float (*Lred)[2] = reinterpret_cast<float(*)[2]>(Asm);
#pragma unroll
  for (int rf = 0; rf < 4; ++rf)
#pragma unroll
    for (int r = 0; r < 4; ++r) {
      float v = lpart[rf][r];
      v += __shfl_xor(v, 1);
      v += __shfl_xor(v, 2);
      v += __shfl_xor(v, 4);
      v += __shfl_xor(v, 8);
      if (c == 0) Lred[wr * 64 + rf * 16 + g * 4 + r][wc] = v;
    }
  __syncthreads();
  if (tid < 128)
    Lpart[(size_t)s * N_ + row0 + tid] = Lred[tid][0] + Lred[tid][1];

  float* ob = Opart + ((size_t)s * N_ + row0) * C_;
#pragma unroll
  for (int rf = 0; rf < 4; ++rf)
#pragma unroll
    for (int cf = 0; cf < 4; ++cf)
#pragma unroll
      for (int r = 0; r < 4; ++r)
        ob[(wr * 64 + rf * 16 + g * 4 + r) * C_ + wc * 64 + cf * 16 + c] = Oacc[rf][cf][r];
}

// row-wise: f32 -> bf16 copy + exact f32 squared norm
__global__ void prep_rows(const float* __restrict__ src, bf16* __restrict__ dst,
                          float* __restrict__ sq)
{
  const int row = blockIdx.x;
  const int t = threadIdx.x;                   // 256 threads, 4 f32 each
  const float4 v = reinterpret_cast<const float4*>(src + (size_t)row * D_)[t];
  float ss = v.x * v.x + v.y * v.y + v.z * v.z + v.w * v.w;
  bf16x4 hv;
  hv[0] = (bf16)v.x; hv[1] = (bf16)v.y; hv[2] = (bf16)v.z; hv[3] = (bf16)v.w;
  *reinterpret_cast<bf16x4*>(dst + (size_t)row * D_ + t * 4) = hv;
#pragma unroll
  for (int o = 32; o > 0; o >>= 1) ss += __shfl_down(ss, o);
  __shared__ float red[4];
  if ((t & 63) == 0) red[t >> 6] = ss;
  __syncthreads();
  if (t == 0) sq[row] = red[0] + red[1] + red[2] + red[3];
}

// y[8192][128] f32 -> yT[128][8192] bf16
__global__ void prep_yT(const float* __restrict__ y, bf16* __restrict__ yT)
{
  __shared__ bf16 tile[C_][72];
  const int m0 = blockIdx.x * 64;
  const int t = threadIdx.x;
#pragma unroll
  for (int i = 0; i < 32; ++i) {
    const int idx = i * 256 + t;               // 0..8191
    const int ml = idx >> 7, cc = idx & 127;
    tile[cc][ml] = (bf16)y[(size_t)(m0 + ml) * C_ + cc];
  }
  __syncthreads();
#pragma unroll
  for (int i = 0; i < 32; ++i) {
    const int idx = i * 256 + t;
    const int cc = idx >> 6, ml = idx & 63;
    yT[(size_t)cc * M_ + m0 + ml] = tile[cc][ml];
  }
}

__global__ void combine(const float* __restrict__ Opart, const float* __restrict__ Lpart,
                        float* __restrict__ out, int split)
{
  const int i = blockIdx.x * 256 + threadIdx.x;   // < N_*C_
  const int row = i >> 7;
  float o = 0.f, l = 0.f;
  for (int s = 0; s < split; ++s) {
    o += Opart[(size_t)s * N_ * C_ + i];
    l += Lpart[(size_t)s * N_ + row];
  }
  out[i] = o / l;
}

extern "C" void kernel_launch(void* const* d_in, const int* in_sizes, int n_in,
                              void* d_out, int out_size, void* d_ws, size_t ws_size,
                              hipStream_t stream)
{
  const float* x  = (const float*)d_in[0];
  const float* xn = (const float*)d_in[1];
  const float* y  = (const float*)d_in[2];
  // d_in[3] = log_T: computed-but-unused in the reference forward.
  float* out = (float*)d_out;

  char* ws = (char*)d_ws;
  bf16*  xb    = (bf16*)(ws);
  bf16*  xnb   = (bf16*)(ws + (size_t)8  * 1024 * 1024);
  bf16*  yT    = (bf16*)(ws + (size_t)24 * 1024 * 1024);
  float* xsq   = (float*)(ws + (size_t)26 * 1024 * 1024);
  float* xnsq  = (float*)(ws + (size_t)26 * 1024 * 1024 + 16 * 1024);
  float* Lpart = (float*)(ws + (size_t)26 * 1024 * 1024 + 48 * 1024);
  float* Opart = (float*)(ws + (size_t)27 * 1024 * 1024);

  // choose split count by available workspace: Opart = split * 2 MiB @ 27 MiB
  int split, shift;
  const size_t MB = 1024 * 1024;
  if      (ws_size >= 91 * MB) { split = 32; shift = 5; }
  else if (ws_size >= 59 * MB) { split = 16; shift = 4; }
  else                         { split = 8;  shift = 3; }
  const int mcols = M_ / split;
  const int nbn   = mcols / BN;

  prep_rows<<<N_, 256, 0, stream>>>(x, xb, xsq);
  prep_rows<<<M_, 256, 0, stream>>>(xn, xnb, xnsq);
  prep_yT<<<M_ / 64, 256, 0, stream>>>(y, yT);
  nona_main<<<(N_ / BM) * split, 256, 0, stream>>>(xb, xnb, yT, xsq, xnsq, Opart, Lpart,
                                                   split - 1, shift, mcols, nbn);
  combine<<<(N_ * C_) / 256, 256, 0, stream>>>(Opart, Lpart, out, split);
}

// Round 3
// 254.064 us; speedup vs baseline: 1.5842x; 1.5040x over previous
//
#include <hip/hip_runtime.h>

// NONA: out = softmax(-cdist(x, x_n), axis=1) @ y
//   x[4096,1024] f32, x_n[8192,1024] f32, y[8192,128] f32, log_T unused.
//
// R3 changes (R2 was latency-bound: serial stage->drain->compute K-loop,
// MfmaUtil 9% with everything idle):
//  * T3-minimum pipelined K-loop: A/B double-buffered; per iteration
//    { __syncthreads() (implicit vmcnt(0) drain of PREVIOUS stage);
//      STAGE(kk+1 -> other buf); MFMA(cur buf) }  -> loads overlap a full
//    compute phase. Barriers 38 -> 19 per bn.
//  * V(h1) prefetched into the dead B0 slot at kk=15; P halves go into dead
//    A0/B1 slots. LDS = 5 x 16K = 80K -> 2 blocks/CU.
//  * T5 setprio(1) around MFMA clusters.
//
// ws layout (bytes): xb@0 (8Mi) | xnb@8Mi (16Mi) | yT@24Mi (2Mi) |
//   xsq@26Mi (16Ki) | xnsq@+16Ki (32Ki) | Lpart@26Mi+48Ki (<=512Ki) |
//   Opart@27Mi (split*2Mi)

#define N_ 4096
#define M_ 8192
#define D_ 1024
#define C_ 128
#define BM 128
#define BN 128
#define BK 64
#define NKK (D_ / BK)        // 16

typedef __bf16 bf16;
typedef __attribute__((ext_vector_type(8))) __bf16 bf16x8;
typedef __attribute__((ext_vector_type(4))) __bf16 bf16x4;
typedef __attribute__((ext_vector_type(4))) float f32x4;

__device__ __forceinline__ void async_copy16(const bf16* gp, void* lp) {
  __builtin_amdgcn_global_load_lds(
      (__attribute__((address_space(1))) void*)const_cast<bf16*>(gp),
      (__attribute__((address_space(3))) void*)lp, 16, 0, 0);
}

// Swizzled LDS byte offset for a [rows][64]-bf16 tile (128 B rows):
// 16B-granule XOR with row&7. Staging stores src granule (g ^ row&7) at
// granule g (linear dest), so reading granule (g ^ row&7) returns src granule g.
__device__ __forceinline__ int swz(int row, int gran) {
  return (row << 7) + ((gran ^ (row & 7)) << 4);
}

// Stage a [128][64]-bf16 tile (16 KiB) global->LDS, source pre-swizzled.
__device__ __forceinline__ void stage16k(const bf16* src, int ld, char* lds, int tid) {
  const int lane = tid & 63, wave = tid >> 6;
#pragma unroll
  for (int j = 0; j < 4; ++j) {
    const int ch  = j * 4 + wave;            // wave-uniform chunk id
    const int off = ch * 1024 + lane * 16;   // linear byte in tile
    const int row = off >> 7;
    const int grs = ((off >> 4) & 7) ^ (row & 7);
    async_copy16(src + (size_t)row * ld + grs * 8, lds + ch * 1024);
  }
}

__global__ __launch_bounds__(256, 2)
void nona_main(const bf16* __restrict__ xb, const bf16* __restrict__ xnb,
               const bf16* __restrict__ yT, const float* __restrict__ xsq,
               const float* __restrict__ xnsq, float* __restrict__ Opart,
               float* __restrict__ Lpart,
               int split_mask, int split_shift, int mcols, int nbn)
{
  __shared__ __align__(16) char Lds[81920];
  char* const A0  = Lds;                // x tile, even kk; later P(h0)
  char* const A1  = Lds + 16384;        // x tile, odd kk
  char* const B0  = Lds + 32768;        // xn tile, even kk; later V(h1)
  char* const B1  = Lds + 49152;        // xn tile, odd kk; later P(h1)
  char* const Vsm = Lds + 65536;        // yT tile half 0 [128 C][64 xn]

  const int tid  = threadIdx.x;
  const int lane = tid & 63;
  const int wave = tid >> 6;
  const int wr = wave >> 1, wc = wave & 1;
  const int g = lane >> 4, c = lane & 15;

  const int bid  = blockIdx.x;
  const int s    = bid & split_mask;   // split id; bid%8 -> XCD round-robin locality
  const int rb   = bid >> split_shift;
  const int row0 = rb * BM;
  const int col0 = s * mcols;

  float xsqr[4][4];
#pragma unroll
  for (int rf = 0; rf < 4; ++rf)
#pragma unroll
    for (int r = 0; r < 4; ++r)
      xsqr[rf][r] = xsq[row0 + wr * 64 + rf * 16 + g * 4 + r];

  f32x4 Oacc[4][4];
  const f32x4 zero = {0.f, 0.f, 0.f, 0.f};
#pragma unroll
  for (int rf = 0; rf < 4; ++rf)
#pragma unroll
    for (int cf = 0; cf < 4; ++cf) Oacc[rf][cf] = zero;
  float lpart[4][4] = {};

  auto writeP = [&](f32x4 (&w)[4][4], int half, char* Pdst) {
    if (wc == half) {
#pragma unroll
      for (int rf = 0; rf < 4; ++rf)
#pragma unroll
        for (int cf = 0; cf < 4; ++cf)
#pragma unroll
          for (int r = 0; r < 4; ++r) {
            const int row = wr * 64 + rf * 16 + g * 4 + r;
            const int col = cf * 16 + c;                    // xn within half
            const int byte = (row << 7) + (((col >> 3) ^ (row & 7)) << 4) + (col & 7) * 2;
            *(bf16*)(Pdst + byte) = (bf16)w[rf][cf][r];
          }
    }
  };
  auto pvStep = [&](const char* Pp, const char* Vp) {
#pragma unroll
    for (int ks = 0; ks < 2; ++ks) {
      bf16x8 pa[4];
#pragma unroll
      for (int rf = 0; rf < 4; ++rf)
        pa[rf] = *(const bf16x8*)(Pp + swz(wr * 64 + rf * 16 + c, ks * 4 + g));
      __builtin_amdgcn_s_setprio(1);
#pragma unroll
      for (int cf = 0; cf < 4; ++cf) {
        bf16x8 vb = *(const bf16x8*)(Vp + swz(wc * 64 + cf * 16 + c, ks * 4 + g));
#pragma unroll
        for (int rf = 0; rf < 4; ++rf)
          Oacc[rf][cf] = __builtin_amdgcn_mfma_f32_16x16x32_bf16(pa[rf], vb, Oacc[rf][cf], 0, 0, 0);
      }
      __builtin_amdgcn_s_setprio(0);
    }
  };

  for (int bn = 0; bn < nbn; ++bn) {
    const int colbase = col0 + bn * BN;
    const bf16* xA = xb + (size_t)row0 * D_;
    const bf16* xB = xnb + (size_t)colbase * D_;

    f32x4 Sacc[4][4];
#pragma unroll
    for (int rf = 0; rf < 4; ++rf)
#pragma unroll
      for (int cf = 0; cf < 4; ++cf) Sacc[rf][cf] = zero;

    // bn prologue: previous bn's PV readers (B0=V(h1), B1=P(h1)) + Vsm done
    __syncthreads();
    stage16k(xA, D_, A0, tid);
    stage16k(xB, D_, B0, tid);
    stage16k(yT + colbase, M_, Vsm, tid);          // V half 0

#pragma unroll 1
    for (int kk = 0; kk < NKK; ++kk) {
      __syncthreads();   // implicit vmcnt(0): stage of buf[kk&1] (+V h0 at kk=0) landed
      if (kk + 1 < NKK) {
        char* An = (kk & 1) ? A0 : A1;             // buffer for kk+1
        char* Bn = (kk & 1) ? B0 : B1;
        stage16k(xA + (kk + 1) * BK, D_, An, tid);
        stage16k(xB + (kk + 1) * BK, D_, Bn, tid);
      } else {
        stage16k(yT + colbase + 64, M_, B0, tid);  // V half 1 -> dead B0 slot
      }
      const char* Ac = (kk & 1) ? A1 : A0;
      const char* Bc = (kk & 1) ? B1 : B0;
#pragma unroll
      for (int ks = 0; ks < 2; ++ks) {
        bf16x8 af[4];
#pragma unroll
        for (int rf = 0; rf < 4; ++rf)
          af[rf] = *(const bf16x8*)(Ac + swz(wr * 64 + rf * 16 + c, ks * 4 + g));
        __builtin_amdgcn_s_setprio(1);
#pragma unroll
        for (int cf = 0; cf < 4; ++cf) {
          bf16x8 bv = *(const bf16x8*)(Bc + swz(wc * 64 + cf * 16 + c, ks * 4 + g));
#pragma unroll
          for (int rf = 0; rf < 4; ++rf)
            Sacc[rf][cf] = __builtin_amdgcn_mfma_f32_16x16x32_bf16(af[rf], bv, Sacc[rf][cf], 0, 0, 0);
        }
        __builtin_amdgcn_s_setprio(0);
      }
    }
    // kk=15 computed A1/B1; A0 free since kk=14; V(h1) loads in flight -> B0

    // elementwise: w = exp(-sqrt(max(xsq + xnsq - 2*dot, 0))); accumulate l
#pragma unroll
    for (int cf = 0; cf < 4; ++cf) {
      const float nsq = xnsq[colbase + wc * 64 + cf * 16 + c];
#pragma unroll
      for (int rf = 0; rf < 4; ++rf)
#pragma unroll
        for (int r = 0; r < 4; ++r) {
          float d2 = xsqr[rf][r] + nsq - 2.0f * Sacc[rf][cf][r];
          d2 = fmaxf(d2, 0.0f);
          const float wv = __expf(-sqrtf(d2));
          lpart[rf][r] += wv;
          Sacc[rf][cf][r] = wv;     // reuse Sacc as w storage
        }
    }

    writeP(Sacc, 0, A0);     // A0 dead since kk=14 (all waves passed kk=15 barrier)
    __syncthreads();         // P(h0) visible; V(h1) loads drained (vmcnt(0)); kk15 readers done
    pvStep(A0, Vsm);         // PV half 0
    writeP(Sacc, 1, B1);     // B1 dead (kk15 readers done at barrier above)
    __syncthreads();         // P(h1) visible; pvStep(h0) readers of A0/Vsm done
    pvStep(B1, B0);          // PV half 1 (V(h1) in B0)
    // next bn's prologue barrier protects B0/B1/Vsm restage
  }

  // ---- epilogue: l reduction (deterministic: shfl + single writer) ----
  __syncthreads();                   // pvStep(h1) readers done; A0 reusable
  float (*Lred)[2] = reinterpret_cast<float(*)[2]>(A0);
#pragma unroll
  for (int rf = 0; rf < 4; ++rf)
#pragma unroll
    for (int r = 0; r < 4; ++r) {
      float v = lpart[rf][r];
      v += __shfl_xor(v, 1);
      v += __shfl_xor(v, 2);
      v += __shfl_xor(v, 4);
      v += __shfl_xor(v, 8);
      if (c == 0) Lred[wr * 64 + rf * 16 + g * 4 + r][wc] = v;
    }
  __syncthreads();
  if (tid < 128)
    Lpart[(size_t)s * N_ + row0 + tid] = Lred[tid][0] + Lred[tid][1];

  float* ob = Opart + ((size_t)s * N_ + row0) * C_;
#pragma unroll
  for (int rf = 0; rf < 4; ++rf)
#pragma unroll
    for (int cf = 0; cf < 4; ++cf)
#pragma unroll
      for (int r = 0; r < 4; ++r)
        ob[(wr * 64 + rf * 16 + g * 4 + r) * C_ + wc * 64 + cf * 16 + c] = Oacc[rf][cf][r];
}

// row-wise: f32 -> bf16 copy + exact f32 squared norm
__global__ void prep_rows(const float* __restrict__ src, bf16* __restrict__ dst,
                          float* __restrict__ sq)
{
  const int row = blockIdx.x;
  const int t = threadIdx.x;                   // 256 threads, 4 f32 each
  const float4 v = reinterpret_cast<const float4*>(src + (size_t)row * D_)[t];
  float ss = v.x * v.x + v.y * v.y + v.z * v.z + v.w * v.w;
  bf16x4 hv;
  hv[0] = (bf16)v.x; hv[1] = (bf16)v.y; hv[2] = (bf16)v.z; hv[3] = (bf16)v.w;
  *reinterpret_cast<bf16x4*>(dst + (size_t)row * D_ + t * 4) = hv;
#pragma unroll
  for (int o = 32; o > 0; o >>= 1) ss += __shfl_down(ss, o);
  __shared__ float red[4];
  if ((t & 63) == 0) red[t >> 6] = ss;
  __syncthreads();
  if (t == 0) sq[row] = red[0] + red[1] + red[2] + red[3];
}

// y[8192][128] f32 -> yT[128][8192] bf16
__global__ void prep_yT(const float* __restrict__ y, bf16* __restrict__ yT)
{
  __shared__ bf16 tile[C_][72];
  const int m0 = blockIdx.x * 64;
  const int t = threadIdx.x;
#pragma unroll
  for (int i = 0; i < 32; ++i) {
    const int idx = i * 256 + t;               // 0..8191
    const int ml = idx >> 7, cc = idx & 127;
    tile[cc][ml] = (bf16)y[(size_t)(m0 + ml) * C_ + cc];
  }
  __syncthreads();
#pragma unroll
  for (int i = 0; i < 32; ++i) {
    const int idx = i * 256 + t;
    const int cc = idx >> 6, ml = idx & 63;
    yT[(size_t)cc * M_ + m0 + ml] = tile[cc][ml];
  }
}

__global__ void combine(const float* __restrict__ Opart, const float* __restrict__ Lpart,
                        float* __restrict__ out, int split)
{
  const int i = blockIdx.x * 256 + threadIdx.x;   // < N_*C_
  const int row = i >> 7;
  float o = 0.f, l = 0.f;
  for (int s = 0; s < split; ++s) {
    o += Opart[(size_t)s * N_ * C_ + i];
    l += Lpart[(size_t)s * N_ + row];
  }
  out[i] = o / l;
}

extern "C" void kernel_launch(void* const* d_in, const int* in_sizes, int n_in,
                              void* d_out, int out_size, void* d_ws, size_t ws_size,
                              hipStream_t stream)
{
  const float* x  = (const float*)d_in[0];
  const float* xn = (const float*)d_in[1];
  const float* y  = (const float*)d_in[2];
  // d_in[3] = log_T: computed-but-unused in the reference forward.
  float* out = (float*)d_out;

  char* ws = (char*)d_ws;
  bf16*  xb    = (bf16*)(ws);
  bf16*  xnb   = (bf16*)(ws + (size_t)8  * 1024 * 1024);
  bf16*  yT    = (bf16*)(ws + (size_t)24 * 1024 * 1024);
  float* xsq   = (float*)(ws + (size_t)26 * 1024 * 1024);
  float* xnsq  = (float*)(ws + (size_t)26 * 1024 * 1024 + 16 * 1024);
  float* Lpart = (float*)(ws + (size_t)26 * 1024 * 1024 + 48 * 1024);
  float* Opart = (float*)(ws + (size_t)27 * 1024 * 1024);

  // choose split count by available workspace: Opart = split * 2 MiB @ 27 MiB
  int split, shift;
  const size_t MB = 1024 * 1024;
  if      (ws_size >= 91 * MB) { split = 32; shift = 5; }
  else if (ws_size >= 59 * MB) { split = 16; shift = 4; }
  else                         { split = 8;  shift = 3; }
  const int mcols = M_ / split;
  const int nbn   = mcols / BN;

  prep_rows<<<N_, 256, 0, stream>>>(x, xb, xsq);
  prep_rows<<<M_, 256, 0, stream>>>(xn, xnb, xnsq);
  prep_yT<<<M_ / 64, 256, 0, stream>>>(y, yT);
  nona_main<<<(N_ / BM) * split, 256, 0, stream>>>(xb, xnb, yT, xsq, xnsq, Opart, Lpart,
                                                   split - 1, shift, mcols, nbn);
  combine<<<(N_ * C_) / 256, 256, 0, stream>>>(Opart, Lpart, out, split);
}

// Round 4
// 213.850 us; speedup vs baseline: 1.8821x; 1.1880x over previous
//
#include <hip/hip_runtime.h>

// NONA: out = softmax(-cdist(x, x_n), axis=1) @ y
//   x[4096,1024] f32, x_n[8192,1024] f32, y[8192,128] f32, log_T unused.
//
// R4 changes (R3 was latency-bound at 2 blocks/CU: phase ~1100cy vs ~500cy
// compute content; LDS 80K capped co-residency):
//  * tile BM=128 x BN=64, 4 waves each owning 32 rows x 64 cols.
//    LDS = A-dbuf 2x16K + B-dbuf 2x8K = 48K -> 3 blocks/CU (m97 regime).
//    V ([128C][64]) stages into dead A0 at kk=15; P ([128][64]) into dead A1.
//    All tiles keep the proven 128-B-row XOR-granule swizzle (0 conflicts).
//  * per-wave full-row ownership -> single PV step, no wc split, L-reduce
//    without LDS.
//  * split tiers now 64/32/16/8 by ws_size so grid >= 768 when possible.
//
// ws layout (bytes): xb@0 (8Mi) | xnb@8Mi (16Mi) | yT@24Mi (2Mi) |
//   xsq@26Mi (16Ki) | xnsq@+16Ki (32Ki) | Lpart@26Mi+48Ki (<=1Mi) |
//   Opart@28Mi (split*2Mi)

#define N_ 4096
#define M_ 8192
#define D_ 1024
#define C_ 128
#define BM 128
#define BN 64
#define BK 64
#define NKK (D_ / BK)        // 16

typedef __bf16 bf16;
typedef __attribute__((ext_vector_type(8))) __bf16 bf16x8;
typedef __attribute__((ext_vector_type(4))) __bf16 bf16x4;
typedef __attribute__((ext_vector_type(4))) float f32x4;

__device__ __forceinline__ void async_copy16(const bf16* gp, void* lp) {
  __builtin_amdgcn_global_load_lds(
      (__attribute__((address_space(1))) void*)const_cast<bf16*>(gp),
      (__attribute__((address_space(3))) void*)lp, 16, 0, 0);
}

// Swizzled LDS byte offset for a [rows][64]-bf16 tile (128 B rows):
// 16B-granule XOR with row&7. Staging stores src granule (g ^ row&7) at
// granule g (linear dest), so reading granule (g ^ row&7) returns src granule g.
__device__ __forceinline__ int swz(int row, int gran) {
  return (row << 7) + ((gran ^ (row & 7)) << 4);
}

// Stage NCH KiB-chunks of a [*][64]-bf16 tile global->LDS, source pre-swizzled.
// NCH=16 -> [128][64] (16 KiB); NCH=8 -> [64][64] (8 KiB).
template <int NCH>
__device__ __forceinline__ void stage(const bf16* src, int ld, char* lds, int tid) {
  const int lane = tid & 63, wave = tid >> 6;
#pragma unroll
  for (int j = 0; j < NCH / 4; ++j) {
    const int ch  = j * 4 + wave;            // wave-uniform chunk id
    const int off = ch * 1024 + lane * 16;   // linear byte in tile
    const int row = off >> 7;
    const int grs = ((off >> 4) & 7) ^ (row & 7);
    async_copy16(src + (size_t)row * ld + grs * 8, lds + ch * 1024);
  }
}

__global__ __launch_bounds__(256, 3)
void nona_main(const bf16* __restrict__ xb, const bf16* __restrict__ xnb,
               const bf16* __restrict__ yT, const float* __restrict__ xsq,
               const float* __restrict__ xnsq, float* __restrict__ Opart,
               float* __restrict__ Lpart,
               int split_mask, int split_shift, int mcols, int nbn)
{
  __shared__ __align__(16) char Lds[49152];
  char* const A0 = Lds;            // x [128][64], even kk; tail: V [128 C][64]
  char* const A1 = Lds + 16384;    // x [128][64], odd kk;  tail: P [128][64]
  char* const B0 = Lds + 32768;    // xn [64][64], even kk
  char* const B1 = Lds + 40960;    // xn [64][64], odd kk

  const int tid  = threadIdx.x;
  const int lane = tid & 63;
  const int wave = tid >> 6;          // wave owns rows wave*32..+32
  const int g = lane >> 4, c = lane & 15;

  const int bid  = blockIdx.x;
  const int s    = bid & split_mask;  // split id; bid%8 -> XCD round-robin locality
  const int rb   = bid >> split_shift;
  const int row0 = rb * BM;
  const int col0 = s * mcols;

  float xsqr[2][4];
#pragma unroll
  for (int rf = 0; rf < 2; ++rf)
#pragma unroll
    for (int r = 0; r < 4; ++r)
      xsqr[rf][r] = xsq[row0 + wave * 32 + rf * 16 + g * 4 + r];

  f32x4 Oacc[2][8];
  const f32x4 zero = {0.f, 0.f, 0.f, 0.f};
#pragma unroll
  for (int rf = 0; rf < 2; ++rf)
#pragma unroll
    for (int cc = 0; cc < 8; ++cc) Oacc[rf][cc] = zero;
  float lpart[2][4] = {};

  for (int bn = 0; bn < nbn; ++bn) {
    const int colbase = col0 + bn * BN;
    const bf16* xA = xb + (size_t)row0 * D_;
    const bf16* xB = xnb + (size_t)colbase * D_;

    f32x4 Sacc[2][4];
#pragma unroll
    for (int rf = 0; rf < 2; ++rf)
#pragma unroll
      for (int cf = 0; cf < 4; ++cf) Sacc[rf][cf] = zero;

    __syncthreads();                 // prologue: prev bn's PV readers of A0/A1 done
    stage<16>(xA, D_, A0, tid);
    stage<8>(xB, D_, B0, tid);

#pragma unroll 1
    for (int kk = 0; kk < NKK; ++kk) {
      __syncthreads();   // implicit vmcnt(0): stage of buf[kk&1] landed; dest bufs dead
      if (kk + 1 < NKK) {
        stage<16>(xA + (kk + 1) * BK, D_, (kk & 1) ? A0 : A1, tid);
        stage<8>(xB + (kk + 1) * BK, D_, (kk & 1) ? B0 : B1, tid);
      } else {
        stage<16>(yT + colbase, M_, A0, tid);   // V tile -> dead A0
      }
      const char* Ac = (kk & 1) ? A1 : A0;
      const char* Bc = (kk & 1) ? B1 : B0;
#pragma unroll
      for (int ks = 0; ks < 2; ++ks) {
        bf16x8 af[2];
#pragma unroll
        for (int rf = 0; rf < 2; ++rf)
          af[rf] = *(const bf16x8*)(Ac + swz(wave * 32 + rf * 16 + c, ks * 4 + g));
        __builtin_amdgcn_s_setprio(1);
#pragma unroll
        for (int cf = 0; cf < 4; ++cf) {
          bf16x8 bv = *(const bf16x8*)(Bc + swz(cf * 16 + c, ks * 4 + g));
#pragma unroll
          for (int rf = 0; rf < 2; ++rf)
            Sacc[rf][cf] = __builtin_amdgcn_mfma_f32_16x16x32_bf16(af[rf], bv, Sacc[rf][cf], 0, 0, 0);
        }
        __builtin_amdgcn_s_setprio(0);
      }
    }

    // elementwise: w = exp(-sqrt(max(xsq + xnsq - 2*dot, 0))); accumulate l
#pragma unroll
    for (int cf = 0; cf < 4; ++cf) {
      const float nsq = xnsq[colbase + cf * 16 + c];
#pragma unroll
      for (int rf = 0; rf < 2; ++rf)
#pragma unroll
        for (int r = 0; r < 4; ++r) {
          float d2 = xsqr[rf][r] + nsq - 2.0f * Sacc[rf][cf][r];
          d2 = fmaxf(d2, 0.0f);
          const float wv = __expf(-sqrtf(d2));
          lpart[rf][r] += wv;
          Sacc[rf][cf][r] = wv;     // reuse Sacc as w storage
        }
    }

    __syncthreads();                 // (a) kk=15 readers of A1/B1 done; V drained into A0
    // write P -> A1 (each wave writes its own 32 rows, all 64 cols)
#pragma unroll
    for (int rf = 0; rf < 2; ++rf)
#pragma unroll
      for (int cf = 0; cf < 4; ++cf)
#pragma unroll
        for (int r = 0; r < 4; ++r) {
          const int row = wave * 32 + rf * 16 + g * 4 + r;
          const int col = cf * 16 + c;
          const int byte = (row << 7) + (((col >> 3) ^ (row & 7)) << 4) + (col & 7) * 2;
          *(bf16*)(A1 + byte) = (bf16)Sacc[rf][cf][r];
        }
    __syncthreads();                 // (b) P visible
    // PV: O[32 x 128C] += P[32 x 64] @ V^T (V stored [128C][64])
#pragma unroll
    for (int ks = 0; ks < 2; ++ks) {
      bf16x8 pa[2];
#pragma unroll
      for (int rf = 0; rf < 2; ++rf)
        pa[rf] = *(const bf16x8*)(A1 + swz(wave * 32 + rf * 16 + c, ks * 4 + g));
      __builtin_amdgcn_s_setprio(1);
#pragma unroll
      for (int cc = 0; cc < 8; ++cc) {
        bf16x8 vb = *(const bf16x8*)(A0 + swz(cc * 16 + c, ks * 4 + g));
#pragma unroll
        for (int rf = 0; rf < 2; ++rf)
          Oacc[rf][cc] = __builtin_amdgcn_mfma_f32_16x16x32_bf16(pa[rf], vb, Oacc[rf][cc], 0, 0, 0);
      }
      __builtin_amdgcn_s_setprio(0);
    }
    // next bn's prologue barrier protects A0/B0 restage vs PV readers
  }

  // ---- epilogue: per-row l (sum over the 16 c-lanes; no LDS needed) ----
#pragma unroll
  for (int rf = 0; rf < 2; ++rf)
#pragma unroll
    for (int r = 0; r < 4; ++r) {
      float v = lpart[rf][r];
      v += __shfl_xor(v, 1);
      v += __shfl_xor(v, 2);
      v += __shfl_xor(v, 4);
      v += __shfl_xor(v, 8);
      if (c == 0)
        Lpart[(size_t)s * N_ + row0 + wave * 32 + rf * 16 + g * 4 + r] = v;
    }

  float* ob = Opart + ((size_t)s * N_ + row0) * C_;
#pragma unroll
  for (int rf = 0; rf < 2; ++rf)
#pragma unroll
    for (int cc = 0; cc < 8; ++cc)
#pragma unroll
      for (int r = 0; r < 4; ++r)
        ob[(wave * 32 + rf * 16 + g * 4 + r) * C_ + cc * 16 + c] = Oacc[rf][cc][r];
}

// row-wise: f32 -> bf16 copy + exact f32 squared norm
__global__ void prep_rows(const float* __restrict__ src, bf16* __restrict__ dst,
                          float* __restrict__ sq)
{
  const int row = blockIdx.x;
  const int t = threadIdx.x;                   // 256 threads, 4 f32 each
  const float4 v = reinterpret_cast<const float4*>(src + (size_t)row * D_)[t];
  float ss = v.x * v.x + v.y * v.y + v.z * v.z + v.w * v.w;
  bf16x4 hv;
  hv[0] = (bf16)v.x; hv[1] = (bf16)v.y; hv[2] = (bf16)v.z; hv[3] = (bf16)v.w;
  *reinterpret_cast<bf16x4*>(dst + (size_t)row * D_ + t * 4) = hv;
#pragma unroll
  for (int o = 32; o > 0; o >>= 1) ss += __shfl_down(ss, o);
  __shared__ float red[4];
  if ((t & 63) == 0) red[t >> 6] = ss;
  __syncthreads();
  if (t == 0) sq[row] = red[0] + red[1] + red[2] + red[3];
}

// y[8192][128] f32 -> yT[128][8192] bf16
__global__ void prep_yT(const float* __restrict__ y, bf16* __restrict__ yT)
{
  __shared__ bf16 tile[C_][72];
  const int m0 = blockIdx.x * 64;
  const int t = threadIdx.x;
#pragma unroll
  for (int i = 0; i < 32; ++i) {
    const int idx = i * 256 + t;               // 0..8191
    const int ml = idx >> 7, cc = idx & 127;
    tile[cc][ml] = (bf16)y[(size_t)(m0 + ml) * C_ + cc];
  }
  __syncthreads();
#pragma unroll
  for (int i = 0; i < 32; ++i) {
    const int idx = i * 256 + t;
    const int cc = idx >> 6, ml = idx & 63;
    yT[(size_t)cc * M_ + m0 + ml] = tile[cc][ml];
  }
}

__global__ void combine(const float* __restrict__ Opart, const float* __restrict__ Lpart,
                        float* __restrict__ out, int split)
{
  const int i = blockIdx.x * 256 + threadIdx.x;   // < N_*C_
  const int row = i >> 7;
  float o = 0.f, l = 0.f;
  for (int s = 0; s < split; ++s) {
    o += Opart[(size_t)s * N_ * C_ + i];
    l += Lpart[(size_t)s * N_ + row];
  }
  out[i] = o / l;
}

extern "C" void kernel_launch(void* const* d_in, const int* in_sizes, int n_in,
                              void* d_out, int out_size, void* d_ws, size_t ws_size,
                              hipStream_t stream)
{
  const float* x  = (const float*)d_in[0];
  const float* xn = (const float*)d_in[1];
  const float* y  = (const float*)d_in[2];
  // d_in[3] = log_T: computed-but-unused in the reference forward.
  float* out = (float*)d_out;

  char* ws = (char*)d_ws;
  bf16*  xb    = (bf16*)(ws);
  bf16*  xnb   = (bf16*)(ws + (size_t)8  * 1024 * 1024);
  bf16*  yT    = (bf16*)(ws + (size_t)24 * 1024 * 1024);
  float* xsq   = (float*)(ws + (size_t)26 * 1024 * 1024);
  float* xnsq  = (float*)(ws + (size_t)26 * 1024 * 1024 + 16 * 1024);
  float* Lpart = (float*)(ws + (size_t)26 * 1024 * 1024 + 48 * 1024);
  float* Opart = (float*)(ws + (size_t)28 * 1024 * 1024);

  // choose split count by available workspace: Opart = split * 2 MiB @ 28 MiB
  int split, shift;
  const size_t MB = 1024 * 1024;
  if      (ws_size >= 157 * MB) { split = 64; shift = 6; }
  else if (ws_size >= 93  * MB) { split = 32; shift = 5; }
  else if (ws_size >= 61  * MB) { split = 16; shift = 4; }
  else                          { split = 8;  shift = 3; }
  const int mcols = M_ / split;
  const int nbn   = mcols / BN;

  prep_rows<<<N_, 256, 0, stream>>>(x, xb, xsq);
  prep_rows<<<M_, 256, 0, stream>>>(xn, xnb, xnsq);
  prep_yT<<<M_ / 64, 256, 0, stream>>>(y, yT);
  nona_main<<<(N_ / BM) * split, 256, 0, stream>>>(xb, xnb, yT, xsq, xnsq, Opart, Lpart,
                                                   split - 1, shift, mcols, nbn);
  combine<<<(N_ * C_) / 256, 256, 0, stream>>>(Opart, Lpart, out, split);
}

// Round 5
// 162.800 us; speedup vs baseline: 2.4723x; 1.3136x over previous
//
#include <hip/hip_runtime.h>

// NONA: out = softmax(-cdist(x, x_n), axis=1) @ y
//   x[4096,1024] f32, x_n[8192,1024] f32, y[8192,128] f32, log_T unused.
//
// R5 changes (R4 was per-phase-stall bound: vmcnt(0) drain + barrier skew at
// every K-step; MfmaUtil 18.8% with LDS/MFMA/HBM all <45% of their ceilings):
//  * T4 counted-vmcnt K-loop with raw s_barrier pairs:
//      iter kk: stage(kk+1) -> buf^1           (6 global_load_lds)
//               s_waitcnt vmcnt(6)             (own stage(kk) landed; 6 newest in flight)
//               s_barrier                      (all waves' stage(kk) landed)
//               sched_barrier(0); ds_read+MFMA (compiler emits lgkmcnt)
//               sched_barrier(0); s_barrier    (reads of buf[kk&1] done -> WAR safe)
//    vmcnt never drains to 0 inside the loop (only at the bn-tail seam).
//    Hazards: WAR stage(kk+1) vs qkStep(kk-1) readers -> bar2 of kk-1.
//             RAW qkStep(kk) vs all waves' stage(kk) -> per-wave vmcnt + bar1.
//  * swapped S-MFMA: Sacc = mfma(A=xn_frag, B=x_frag) -> lane holds P for 4
//    CONSECUTIVE xn at one x-row => P-write = 8x ds_write_b64 (2-way bank = free),
//    xnsq as float4 loads, L-reduce = 2 shuffles. Cuts per-bn serial VALU tail.
//  * unchanged: 48K LDS / 3 blocks/CU, XOR-granule swizzle, setprio, split tiers.
//
// ws layout (bytes): xb@0 (8Mi) | xnb@8Mi (16Mi) | yT@24Mi (2Mi) |
//   xsq@26Mi (16Ki) | xnsq@+16Ki (32Ki) | Lpart@26Mi+48Ki (<=1Mi) |
//   Opart@28Mi (split*2Mi)

#define N_ 4096
#define M_ 8192
#define D_ 1024
#define C_ 128
#define BM 128
#define BN 64
#define BK 64
#define NKK (D_ / BK)        // 16

typedef __bf16 bf16;
typedef __attribute__((ext_vector_type(8))) __bf16 bf16x8;
typedef __attribute__((ext_vector_type(4))) __bf16 bf16x4;
typedef __attribute__((ext_vector_type(4))) float f32x4;

__device__ __forceinline__ void async_copy16(const bf16* gp, void* lp) {
  __builtin_amdgcn_global_load_lds(
      (__attribute__((address_space(1))) void*)const_cast<bf16*>(gp),
      (__attribute__((address_space(3))) void*)lp, 16, 0, 0);
}

// Swizzled LDS byte offset for a [rows][64]-bf16 tile (128 B rows):
// 16B-granule XOR with row&7. Staging stores src granule (g ^ row&7) at
// granule g (linear dest), so reading granule (g ^ row&7) returns src granule g.
__device__ __forceinline__ int swz(int row, int gran) {
  return (row << 7) + ((gran ^ (row & 7)) << 4);
}

// Stage NCH KiB-chunks of a [*][64]-bf16 tile global->LDS, source pre-swizzled.
// NCH=16 -> [128][64] (16 KiB, 4 loads/wave); NCH=8 -> [64][64] (8 KiB, 2 loads/wave).
template <int NCH>
__device__ __forceinline__ void stage(const bf16* src, int ld, char* lds, int tid) {
  const int lane = tid & 63, wave = tid >> 6;
#pragma unroll
  for (int j = 0; j < NCH / 4; ++j) {
    const int ch  = j * 4 + wave;            // wave-uniform chunk id
    const int off = ch * 1024 + lane * 16;   // linear byte in tile
    const int row = off >> 7;
    const int grs = ((off >> 4) & 7) ^ (row & 7);
    async_copy16(src + (size_t)row * ld + grs * 8, lds + ch * 1024);
  }
}

__global__ __launch_bounds__(256, 3)
void nona_main(const bf16* __restrict__ xb, const bf16* __restrict__ xnb,
               const bf16* __restrict__ yT, const float* __restrict__ xsq,
               const float* __restrict__ xnsq, float* __restrict__ Opart,
               float* __restrict__ Lpart,
               int split_mask, int split_shift, int mcols, int nbn)
{
  __shared__ __align__(16) char Lds[49152];
  char* const A0 = Lds;            // x [128][64], even kk; tail: V [128 C][64]
  char* const A1 = Lds + 16384;    // x [128][64], odd kk;  tail: P [128][64]
  char* const B0 = Lds + 32768;    // xn [64][64], even kk
  char* const B1 = Lds + 40960;    // xn [64][64], odd kk

  const int tid  = threadIdx.x;
  const int lane = tid & 63;
  const int wave = tid >> 6;          // wave owns x rows wave*32..+32
  const int g = lane >> 4, c = lane & 15;

  const int bid  = blockIdx.x;
  const int s    = bid & split_mask;  // split id; bid%8 -> XCD round-robin locality
  const int rb   = bid >> split_shift;
  const int row0 = rb * BM;
  const int col0 = s * mcols;

  // swapped-S: lane's x rows are wave*32 + rf*16 + c (2 rows total)
  float xs[2];
#pragma unroll
  for (int rf = 0; rf < 2; ++rf)
    xs[rf] = xsq[row0 + wave * 32 + rf * 16 + c];

  f32x4 Oacc[2][8];
  const f32x4 zero = {0.f, 0.f, 0.f, 0.f};
#pragma unroll
  for (int rf = 0; rf < 2; ++rf)
#pragma unroll
    for (int cc = 0; cc < 8; ++cc) Oacc[rf][cc] = zero;
  float lsum[2] = {0.f, 0.f};

  f32x4 Sacc[2][4];

  // S^T step: Sacc[rf][cf] = mfma(A = xn_frag, B = x_frag) ->
  // lane holds P[xn = cf*16 + g*4 + r][x = wave*32 + rf*16 + c]
  auto qkStep = [&](const char* Ac, const char* Bc) {
#pragma unroll
    for (int ks = 0; ks < 2; ++ks) {
      bf16x8 af[2];
#pragma unroll
      for (int rf = 0; rf < 2; ++rf)
        af[rf] = *(const bf16x8*)(Ac + swz(wave * 32 + rf * 16 + c, ks * 4 + g));
      __builtin_amdgcn_s_setprio(1);
#pragma unroll
      for (int cf = 0; cf < 4; ++cf) {
        bf16x8 bv = *(const bf16x8*)(Bc + swz(cf * 16 + c, ks * 4 + g));
#pragma unroll
        for (int rf = 0; rf < 2; ++rf)
          Sacc[rf][cf] = __builtin_amdgcn_mfma_f32_16x16x32_bf16(bv, af[rf], Sacc[rf][cf], 0, 0, 0);
      }
      __builtin_amdgcn_s_setprio(0);
    }
  };

  for (int bn = 0; bn < nbn; ++bn) {
    const int colbase = col0 + bn * BN;
    const bf16* xA = xb + (size_t)row0 * D_;
    const bf16* xB = xnb + (size_t)colbase * D_;

#pragma unroll
    for (int rf = 0; rf < 2; ++rf)
#pragma unroll
      for (int cf = 0; cf < 4; ++cf) Sacc[rf][cf] = zero;

    __syncthreads();                 // prev bn's PV readers of A0(V)/A1(P) done; vm=0
    stage<16>(xA, D_, A0, tid);      // stage(0): 6 loads
    stage<8>(xB, D_, B0, tid);

#pragma unroll 1
    for (int kk = 0; kk < NKK - 1; ++kk) {
      // WAR: buf[(kk+1)&1] last read at qkStep(kk-1), protected by bar2 below.
      stage<16>(xA + (kk + 1) * BK, D_, (kk & 1) ? A0 : A1, tid);
      stage<8>(xB + (kk + 1) * BK, D_, (kk & 1) ? B0 : B1, tid);
      asm volatile("s_waitcnt vmcnt(6)" ::: "memory");   // own stage(kk) landed
      __builtin_amdgcn_s_barrier();                      // bar1: all stage(kk) landed
      __builtin_amdgcn_sched_barrier(0);
      qkStep((kk & 1) ? A1 : A0, (kk & 1) ? B1 : B0);
      __builtin_amdgcn_sched_barrier(0);
      __builtin_amdgcn_s_barrier();                      // bar2: buf[kk&1] reads done
    }
    // peeled kk = 15 (odd): compute A1/B1; stage V -> dead A0 (bar2 of kk=14 passed)
    stage<16>(yT + colbase, M_, A0, tid);                // 4 loads
    asm volatile("s_waitcnt vmcnt(4)" ::: "memory");     // stage(15) landed
    __builtin_amdgcn_s_barrier();
    __builtin_amdgcn_sched_barrier(0);
    qkStep(A1, B1);

    // elementwise: w = exp(-sqrt(max(xsq + xnsq - 2*dot, 0))); accumulate l.
    // Pure VALU, no LDS deps -> runs while V loads fly.
#pragma unroll
    for (int cf = 0; cf < 4; ++cf) {
      const float4 nsq4 = *(const float4*)(xnsq + colbase + cf * 16 + g * 4);
#pragma unroll
      for (int rf = 0; rf < 2; ++rf)
#pragma unroll
        for (int r = 0; r < 4; ++r) {
          float d2 = xs[rf] + ((const float*)&nsq4)[r] - 2.0f * Sacc[rf][cf][r];
          d2 = fmaxf(d2, 0.0f);
          const float wv = __expf(-sqrtf(d2));
          lsum[rf] += wv;
          Sacc[rf][cf][r] = wv;     // reuse Sacc as w storage
        }
    }

    __syncthreads();   // drains vmcnt(0): V landed; all waves done qkStep(15) -> A1 free
    // P-write -> A1: lane writes 4 consecutive xn (8 B) per (rf,cf): ds_write_b64
#pragma unroll
    for (int rf = 0; rf < 2; ++rf)
#pragma unroll
      for (int cf = 0; cf < 4; ++cf) {
        bf16x4 pk;
#pragma unroll
        for (int r = 0; r < 4; ++r) pk[r] = (bf16)Sacc[rf][cf][r];
        const int row  = wave * 32 + rf * 16 + c;
        const int gi   = 2 * cf + (g >> 1);
        const int byte = (row << 7) + ((gi ^ (row & 7)) << 4) + 8 * (g & 1);
        *(bf16x4*)(A1 + byte) = pk;
      }
    __syncthreads();                 // P visible
    // PV: O[32 x 128C] += P[32 x 64] @ V^T (V stored [128C][64])
#pragma unroll
    for (int ks = 0; ks < 2; ++ks) {
      bf16x8 pa[2];
#pragma unroll
      for (int rf = 0; rf < 2; ++rf)
        pa[rf] = *(const bf16x8*)(A1 + swz(wave * 32 + rf * 16 + c, ks * 4 + g));
      __builtin_amdgcn_s_setprio(1);
#pragma unroll
      for (int cc = 0; cc < 8; ++cc) {
        bf16x8 vb = *(const bf16x8*)(A0 + swz(cc * 16 + c, ks * 4 + g));
#pragma unroll
        for (int rf = 0; rf < 2; ++rf)
          Oacc[rf][cc] = __builtin_amdgcn_mfma_f32_16x16x32_bf16(pa[rf], vb, Oacc[rf][cc], 0, 0, 0);
      }
      __builtin_amdgcn_s_setprio(0);
    }
    // next bn's prologue __syncthreads protects A0/A1/B0 restage vs PV readers
  }

  // ---- epilogue: per-row l: lane's lsum[rf] covers its 16 xn per cf; rows
  // with same c live in lanes {c, c+16, c+32, c+48} -> 2 shuffles.
#pragma unroll
  for (int rf = 0; rf < 2; ++rf) {
    float v = lsum[rf];
    v += __shfl_xor(v, 16);
    v += __shfl_xor(v, 32);
    if (g == 0)
      Lpart[(size_t)s * N_ + row0 + wave * 32 + rf * 16 + c] = v;
  }

  float* ob = Opart + ((size_t)s * N_ + row0) * C_;
#pragma unroll
  for (int rf = 0; rf < 2; ++rf)
#pragma unroll
    for (int cc = 0; cc < 8; ++cc)
#pragma unroll
      for (int r = 0; r < 4; ++r)
        ob[(wave * 32 + rf * 16 + g * 4 + r) * C_ + cc * 16 + c] = Oacc[rf][cc][r];
}

// row-wise: f32 -> bf16 copy + exact f32 squared norm
__global__ void prep_rows(const float* __restrict__ src, bf16* __restrict__ dst,
                          float* __restrict__ sq)
{
  const int row = blockIdx.x;
  const int t = threadIdx.x;                   // 256 threads, 4 f32 each
  const float4 v = reinterpret_cast<const float4*>(src + (size_t)row * D_)[t];
  float ss = v.x * v.x + v.y * v.y + v.z * v.z + v.w * v.w;
  bf16x4 hv;
  hv[0] = (bf16)v.x; hv[1] = (bf16)v.y; hv[2] = (bf16)v.z; hv[3] = (bf16)v.w;
  *reinterpret_cast<bf16x4*>(dst + (size_t)row * D_ + t * 4) = hv;
#pragma unroll
  for (int o = 32; o > 0; o >>= 1) ss += __shfl_down(ss, o);
  __shared__ float red[4];
  if ((t & 63) == 0) red[t >> 6] = ss;
  __syncthreads();
  if (t == 0) sq[row] = red[0] + red[1] + red[2] + red[3];
}

// y[8192][128] f32 -> yT[128][8192] bf16
__global__ void prep_yT(const float* __restrict__ y, bf16* __restrict__ yT)
{
  __shared__ bf16 tile[C_][72];
  const int m0 = blockIdx.x * 64;
  const int t = threadIdx.x;
#pragma unroll
  for (int i = 0; i < 32; ++i) {
    const int idx = i * 256 + t;               // 0..8191
    const int ml = idx >> 7, cc = idx & 127;
    tile[cc][ml] = (bf16)y[(size_t)(m0 + ml) * C_ + cc];
  }
  __syncthreads();
#pragma unroll
  for (int i = 0; i < 32; ++i) {
    const int idx = i * 256 + t;
    const int cc = idx >> 6, ml = idx & 63;
    yT[(size_t)cc * M_ + m0 + ml] = tile[cc][ml];
  }
}

__global__ void combine(const float* __restrict__ Opart, const float* __restrict__ Lpart,
                        float* __restrict__ out, int split)
{
  const int i = blockIdx.x * 256 + threadIdx.x;   // < N_*C_
  const int row = i >> 7;
  float o = 0.f, l = 0.f;
  for (int s = 0; s < split; ++s) {
    o += Opart[(size_t)s * N_ * C_ + i];
    l += Lpart[(size_t)s * N_ + row];
  }
  out[i] = o / l;
}

extern "C" void kernel_launch(void* const* d_in, const int* in_sizes, int n_in,
                              void* d_out, int out_size, void* d_ws, size_t ws_size,
                              hipStream_t stream)
{
  const float* x  = (const float*)d_in[0];
  const float* xn = (const float*)d_in[1];
  const float* y  = (const float*)d_in[2];
  // d_in[3] = log_T: computed-but-unused in the reference forward.
  float* out = (float*)d_out;

  char* ws = (char*)d_ws;
  bf16*  xb    = (bf16*)(ws);
  bf16*  xnb   = (bf16*)(ws + (size_t)8  * 1024 * 1024);
  bf16*  yT    = (bf16*)(ws + (size_t)24 * 1024 * 1024);
  float* xsq   = (float*)(ws + (size_t)26 * 1024 * 1024);
  float* xnsq  = (float*)(ws + (size_t)26 * 1024 * 1024 + 16 * 1024);
  float* Lpart = (float*)(ws + (size_t)26 * 1024 * 1024 + 48 * 1024);
  float* Opart = (float*)(ws + (size_t)28 * 1024 * 1024);

  // choose split count by available workspace: Opart = split * 2 MiB @ 28 MiB
  int split, shift;
  const size_t MB = 1024 * 1024;
  if      (ws_size >= 157 * MB) { split = 64; shift = 6; }
  else if (ws_size >= 93  * MB) { split = 32; shift = 5; }
  else if (ws_size >= 61  * MB) { split = 16; shift = 4; }
  else                          { split = 8;  shift = 3; }
  const int mcols = M_ / split;
  const int nbn   = mcols / BN;

  prep_rows<<<N_, 256, 0, stream>>>(x, xb, xsq);
  prep_rows<<<M_, 256, 0, stream>>>(xn, xnb, xnsq);
  prep_yT<<<M_ / 64, 256, 0, stream>>>(y, yT);
  nona_main<<<(N_ / BM) * split, 256, 0, stream>>>(xb, xnb, yT, xsq, xnsq, Opart, Lpart,
                                                   split - 1, shift, mcols, nbn);
  combine<<<(N_ * C_) / 256, 256, 0, stream>>>(Opart, Lpart, out, split);
}